// Round 5
// baseline (250.771 us; speedup 1.0000x reference)
//
#include <hip/hip_runtime.h>
#include <stdint.h>

typedef __bf16 bf16x8 __attribute__((ext_vector_type(8)));
typedef float f32x4 __attribute__((ext_vector_type(4)));
typedef float f32x16 __attribute__((ext_vector_type(16)));
typedef unsigned short u16x8 __attribute__((ext_vector_type(8)));
typedef uint32_t u32x4 __attribute__((ext_vector_type(4)));

#define D_MODEL 1024
#define T_SEQ 2048
#define BATCH 2
#define NHEAD 16
#define HDIM 64
#define MROWS (BATCH * T_SEQ)          // 4096
#define HEADS_TOTAL (BATCH * NHEAD)    // 32
#define QKV_ELEMS (HEADS_TOTAL * T_SEQ * HDIM)  // 4,194,304 per tensor

// Q scale folded with log2(e) so softmax runs in exp2 domain: 0.125 * log2(e)
#define QSCALE_LOG2 0.1803368801111204f

__device__ __forceinline__ unsigned short f32_to_bf16_rne(float f) {
    uint32_t u = __builtin_bit_cast(uint32_t, f);
    uint32_t r = (u + 0x7FFFu + ((u >> 16) & 1u)) >> 16;
    return (unsigned short)r;
}

__device__ __forceinline__ uint32_t pack2(float a, float b) {
    return (uint32_t)f32_to_bf16_rne(a) | ((uint32_t)f32_to_bf16_rne(b) << 16);
}

__device__ __forceinline__ void gload_lds16(const void* g, void* l) {
    __builtin_amdgcn_global_load_lds(
        (const __attribute__((address_space(1))) void*)g,
        (__attribute__((address_space(3))) void*)l, 16, 0, 0);
}

__device__ __forceinline__ f32x4 mfma_bf16(bf16x8 a, bf16x8 b, f32x4 c) {
    return __builtin_amdgcn_mfma_f32_16x16x32_bf16(a, b, c, 0, 0, 0);
}
__device__ __forceinline__ f32x16 mfma32(bf16x8 a, bf16x8 b, f32x16 c) {
    return __builtin_amdgcn_mfma_f32_32x32x16_bf16(a, b, c, 0, 0, 0);
}

// ---------------- convert x: f32 -> bf16, 8 elems/thread ----------------
__global__ void k_convert(const float4* __restrict__ in, u16x8* __restrict__ out, int n8) {
    int i = blockIdx.x * 256 + threadIdx.x;
    if (i >= n8) return;
    float4 a = in[i * 2];
    float4 b = in[i * 2 + 1];
    u16x8 r;
    r[0] = f32_to_bf16_rne(a.x); r[1] = f32_to_bf16_rne(a.y);
    r[2] = f32_to_bf16_rne(a.z); r[3] = f32_to_bf16_rne(a.w);
    r[4] = f32_to_bf16_rne(b.x); r[5] = f32_to_bf16_rne(b.y);
    r[6] = f32_to_bf16_rne(b.z); r[7] = f32_to_bf16_rne(b.w);
    out[i] = r;
}

// ---------- transpose-convert: in f32 [R][C] -> out bf16 [C][R] ----------
__global__ void k_transpose_conv(const float* __restrict__ in, unsigned short* __restrict__ out,
                                 int R, int C) {
    __shared__ float tile[32][33];
    int nc = C >> 5;
    int tc0 = (blockIdx.x % nc) * 32;
    int tr0 = (blockIdx.x / nc) * 32;
    int tx = threadIdx.x & 31, ty = threadIdx.x >> 5;  // ty 0..7
#pragma unroll
    for (int i = 0; i < 4; ++i) {
        int r = ty * 4 + i;
        tile[r][tx] = in[(size_t)(tr0 + r) * C + tc0 + tx];
    }
    __syncthreads();
#pragma unroll
    for (int i = 0; i < 4; ++i) {
        int c = ty * 4 + i;
        out[(size_t)(tc0 + c) * R + tr0 + tx] = f32_to_bf16_rne(tile[tx][c]);
    }
}

// ---------------- GEMM: C[M][N] = A[M][K](bf16) @ Bt[N][K](bf16) + bias ----------------
// 128x128 tile, BK=32, 256 threads (4 waves 2x2), double-buffered LDS (2-phase pipeline).
template <int EPI>
__global__ __launch_bounds__(256) void k_gemm(const unsigned short* __restrict__ A,
                                              const unsigned short* __restrict__ Bt,
                                              const float* __restrict__ bias,
                                              void* __restrict__ outp,
                                              int M, int N, int K) {
    __shared__ __align__(16) unsigned short As[2][128 * 32];
    __shared__ __align__(16) unsigned short Bs[2][128 * 32];
    const int NB = N >> 7;
    int bm = blockIdx.x / NB, bn = blockIdx.x % NB;
    int tid = threadIdx.x;
    int lane = tid & 63, w = tid >> 6;
    int wr = w >> 1, wc = w & 1;
    int l15 = lane & 15, lg = lane >> 4;

    f32x4 acc[4][4] = {};

    const int nK = K >> 5;
    int c1 = tid, c2 = tid + 256;
    int r1 = c1 >> 2, o1 = (c1 & 3) * 8;
    int r2 = c2 >> 2, o2 = (c2 & 3) * 8;

#define GSTAGE(kt, buf)                                                          \
    do {                                                                         \
        int k0_ = (kt) * 32;                                                     \
        gload_lds16(A + (size_t)(bm * 128 + r1) * K + k0_ + o1,                  \
                    (char*)As[buf] + w * 1024);                                  \
        gload_lds16(A + (size_t)(bm * 128 + r2) * K + k0_ + o2,                  \
                    (char*)As[buf] + 4096 + w * 1024);                           \
        gload_lds16(Bt + (size_t)(bn * 128 + r1) * K + k0_ + o1,                 \
                    (char*)Bs[buf] + w * 1024);                                  \
        gload_lds16(Bt + (size_t)(bn * 128 + r2) * K + k0_ + o2,                 \
                    (char*)Bs[buf] + 4096 + w * 1024);                           \
    } while (0)

    GSTAGE(0, 0);
    __syncthreads();

    for (int kt = 0; kt < nK; ++kt) {
        int cur = kt & 1;
        if (kt + 1 < nK) GSTAGE(kt + 1, cur ^ 1);

        const unsigned short* Ac = As[cur];
        const unsigned short* Bc = Bs[cur];
        bf16x8 af[4], bfr[4];
#pragma unroll
        for (int i = 0; i < 4; ++i)
            af[i] = *(const bf16x8*)(Ac + (wr * 64 + i * 16 + l15) * 32 + lg * 8);
#pragma unroll
        for (int j = 0; j < 4; ++j)
            bfr[j] = *(const bf16x8*)(Bc + (wc * 64 + j * 16 + l15) * 32 + lg * 8);
#pragma unroll
        for (int i = 0; i < 4; ++i)
#pragma unroll
            for (int j = 0; j < 4; ++j)
                acc[i][j] = mfma_bf16(af[i], bfr[j], acc[i][j]);
        __syncthreads();
    }
#undef GSTAGE

    if (EPI == 1) {
        float* out = (float*)outp;
#pragma unroll
        for (int jn = 0; jn < 4; ++jn) {
            int n = bn * 128 + wc * 64 + jn * 16 + l15;
            float bv = bias[n];
#pragma unroll
            for (int i = 0; i < 4; ++i) {
#pragma unroll
                for (int j = 0; j < 4; ++j) {
                    int m = bm * 128 + wr * 64 + i * 16 + lg * 4 + j;
                    out[(size_t)m * N + n] = acc[i][jn][j] + bv;
                }
            }
        }
    } else {
        unsigned short* qkv = (unsigned short*)outp;
#pragma unroll
        for (int jn = 0; jn < 4; ++jn) {
            int n = bn * 128 + wc * 64 + jn * 16 + l15;
            float bv = bias[n];
            int part = n >> 10;          // 0=q 1=k 2=v
            int cc = n & 1023;
            int h = cc >> 6, d = cc & 63;
            float scale = (part == 0) ? QSCALE_LOG2 : 1.0f;
            unsigned short* dst = qkv + (size_t)part * QKV_ELEMS;
#pragma unroll
            for (int i = 0; i < 4; ++i) {
#pragma unroll
                for (int j = 0; j < 4; ++j) {
                    int m = bm * 128 + wr * 64 + i * 16 + lg * 4 + j;
                    int b = m >> 11, t = m & 2047;
                    float v = (acc[i][jn][j] + bv) * scale;
                    dst[((size_t)(b * NHEAD + h) * T_SEQ + t) * HDIM + d] = f32_to_bf16_rne(v);
                }
            }
        }
    }
}

// ---------------- V transpose: [bh][t][d] -> [bh][d][t] ----------------
__global__ void k_transpose_v(const unsigned short* __restrict__ V, unsigned short* __restrict__ Vt) {
    __shared__ unsigned short tile[64][66];
    int bh = blockIdx.x >> 5;
    int t0 = (blockIdx.x & 31) * 64;
    const unsigned short* Vb = V + (size_t)bh * T_SEQ * HDIM;
    unsigned short* Vtb = Vt + (size_t)bh * HDIM * T_SEQ;
    int d = threadIdx.x & 63, tq = threadIdx.x >> 6;
#pragma unroll
    for (int r = 0; r < 16; ++r) {
        int tl = tq * 16 + r;
        tile[tl][d] = Vb[(size_t)(t0 + tl) * HDIM + d];
    }
    __syncthreads();
    int tl = threadIdx.x & 63, dq = threadIdx.x >> 6;
#pragma unroll
    for (int r = 0; r < 16; ++r) {
        int dd = dq * 16 + r;
        Vtb[(size_t)dd * T_SEQ + t0 + tl] = tile[tl][dd];
    }
}

// ---------------- flash attention, 32x32 MFMA, swapped operands ----------------
// grid = 512, xcd-pinned. block = 256 (4 waves x 32 q-rows). KVBLK=64 double-buffered.
// QK^T as mfma(K,Q) -> S^T (q = lane&31 -> lane-local softmax, exp2 domain).
// PV B-fragment built in-register with pack2 (RNE) + pre-selected __shfl_xor(32)
// (semantics-certain; no permlane/cvt_pk asm).
//   S^T C/D layout: q = lane&31, kv_local = (rr&3) + 8*(rr>>2) + 4*hi  (+32*ti)
//   B-frag(ks) elem j needs kv = ks*16 + hi*8 + j:
//     dest hi=0: j0..3 = own regs 8k1+0..3 (PA,PC);  j4..7 = partner's PA,PC
//     dest hi=1: j0..3 = partner's PB,PD;            j4..7 = own PB,PD
// Defer-max: skip O-rescale while tile max grows < 8 (log2 units).
__global__ __launch_bounds__(256) void k_attn(const unsigned short* __restrict__ Qg,
                                              const unsigned short* __restrict__ Kg,
                                              const unsigned short* __restrict__ Vtg,
                                              unsigned short* __restrict__ Og) {
    __shared__ __align__(16) unsigned short Ks[2][64 * 64];
    __shared__ __align__(16) unsigned short Vs[2][64 * 64];

    const int NT = T_SEQ / 64;  // 32
    int bid = blockIdx.x;
    int idx = bid >> 3;
    int bh = (bid & 7) * 4 + (idx >> 4);
    int qt = idx & 15;
    int tid = threadIdx.x;
    int w = tid >> 6, lane = tid & 63;
    int l31 = lane & 31, hi = lane >> 5;
    int r7 = l31 & 7;

    const unsigned short* Qb = Qg + (size_t)bh * T_SEQ * HDIM;
    const unsigned short* Kb = Kg + (size_t)bh * T_SEQ * HDIM;
    const unsigned short* Vb = Vtg + (size_t)bh * HDIM * T_SEQ;

    int q0 = qt * 128 + w * 32;

    bf16x8 qf[4];
#pragma unroll
    for (int ks = 0; ks < 4; ++ks)
        qf[ks] = *(const bf16x8*)(Qb + (size_t)(q0 + l31) * HDIM + ks * 16 + hi * 8);

    f32x16 o_[2] = {};
    float m = -INFINITY, l = 0.f;

#define STAGE(tile, buf)                                                             \
    do {                                                                             \
        int kv0s = (tile) * 64;                                                      \
        _Pragma("unroll") for (int i_ = 0; i_ < 2; ++i_) {                           \
            int c_ = i_ * 256 + tid;                                                 \
            int row_ = c_ >> 3;                                                      \
            int cs_ = (c_ & 7) ^ (row_ & 7);                                         \
            gload_lds16(Kb + (size_t)(kv0s + row_) * HDIM + cs_ * 8,                 \
                        (char*)Ks[buf] + i_ * 4096 + w * 1024);                      \
            gload_lds16(Vb + (size_t)row_ * T_SEQ + kv0s + cs_ * 8,                  \
                        (char*)Vs[buf] + i_ * 4096 + w * 1024);                      \
        }                                                                            \
    } while (0)

    STAGE(0, 0);
    __syncthreads();

    for (int t = 0; t < NT; ++t) {
        int cur = t & 1;
        if (t + 1 < NT) STAGE(t + 1, cur ^ 1);

        const char* Kt = (const char*)Ks[cur];
        const char* Vt_ = (const char*)Vs[cur];

        // QK^T: S^T[kv][q]
        f32x16 s_[2] = {};
#pragma unroll
        for (int ti = 0; ti < 2; ++ti) {
            int row = ti * 32 + l31;
#pragma unroll
            for (int ks = 0; ks < 4; ++ks) {
                bf16x8 kf = *(const bf16x8*)(Kt + row * 128 + ((((ks << 1) | hi) ^ r7) << 4));
                s_[ti] = mfma32(kf, qf[ks], s_[ti]);
            }
        }

        // tree max over 32 lane-local entries + hi-half exchange
        float t16[16];
#pragma unroll
        for (int rr = 0; rr < 16; ++rr) t16[rr] = fmaxf(s_[0][rr], s_[1][rr]);
#pragma unroll
        for (int st = 8; st >= 1; st >>= 1)
#pragma unroll
            for (int rr = 0; rr < 8; ++rr)
                if (rr < st) t16[rr] = fmaxf(t16[rr], t16[rr + st]);
        float mx = fmaxf(t16[0], __shfl_xor(t16[0], 32));

        // deferred rescale (log2 domain, THR = 8)
        if (__any(mx - m > 8.0f)) {
            float mn = fmaxf(m, mx);
            float sc = __builtin_exp2f(m - mn);
            m = mn;
            l *= sc;
#pragma unroll
            for (int rr = 0; rr < 16; ++rr) {
                o_[0][rr] *= sc;
                o_[1][rr] *= sc;
            }
        }

        // P = 2^(s - m); tree-sum into l
        float a16[16];
#pragma unroll
        for (int ti = 0; ti < 2; ++ti)
#pragma unroll
            for (int rr = 0; rr < 16; ++rr) s_[ti][rr] = __builtin_exp2f(s_[ti][rr] - m);
#pragma unroll
        for (int rr = 0; rr < 16; ++rr) a16[rr] = s_[0][rr] + s_[1][rr];
#pragma unroll
        for (int st = 8; st >= 1; st >>= 1)
#pragma unroll
            for (int rr = 0; rr < 8; ++rr)
                if (rr < st) a16[rr] += a16[rr + st];
        l += a16[0] + __shfl_xor(a16[0], 32);

        // build PV B-fragments in-register (pack2 + shfl_xor(32) exchange)
        bf16x8 pa[4];
#pragma unroll
        for (int ks = 0; ks < 4; ++ks) {
            int ti = ks >> 1, k1 = ks & 1;
            uint32_t PA = pack2(s_[ti][8 * k1 + 0], s_[ti][8 * k1 + 1]);
            uint32_t PC = pack2(s_[ti][8 * k1 + 2], s_[ti][8 * k1 + 3]);
            uint32_t PB = pack2(s_[ti][8 * k1 + 4], s_[ti][8 * k1 + 5]);
            uint32_t PD = pack2(s_[ti][8 * k1 + 6], s_[ti][8 * k1 + 7]);
            // each lane sends what its partner needs: lo sends PB/PD, hi sends PA/PC
            uint32_t u0 = hi ? PA : PB;
            uint32_t u1 = hi ? PC : PD;
            uint32_t x0 = (uint32_t)__shfl_xor((int)u0, 32);
            uint32_t x1 = (uint32_t)__shfl_xor((int)u1, 32);
            u32x4 ww;
            ww[0] = hi ? x0 : PA;   // (PA_lo, PB_lo) -> elems 0,1
            ww[1] = hi ? x1 : PC;   // (PC_lo, PD_lo) -> elems 2,3
            ww[2] = hi ? PB : x0;   // (PA_hi, PB_hi) -> elems 4,5
            ww[3] = hi ? PD : x1;   // (PC_hi, PD_hi) -> elems 6,7
            pa[ks] = __builtin_bit_cast(bf16x8, ww);
        }

        // PV: O^T[d][q] += V^T[d][kv] * P^T[kv][q]
#pragma unroll
        for (int dn = 0; dn < 2; ++dn) {
            int row = dn * 32 + l31;
#pragma unroll
            for (int ks = 0; ks < 4; ++ks) {
                bf16x8 vf = *(const bf16x8*)(Vt_ + row * 128 + ((((ks << 1) | hi) ^ r7) << 4));
                o_[dn] = mfma32(vf, pa[ks], o_[dn]);
            }
        }
        __syncthreads();
    }
#undef STAGE

    // epilogue: divide by l, transpose O^T -> O via LDS (reuse dead Ks), store coalesced
    float inv = 1.0f / l;
#pragma unroll
    for (int rr = 0; rr < 16; ++rr) {
        o_[0][rr] *= inv;
        o_[1][rr] *= inv;
    }
    char* eB = (char*)Ks + (size_t)w * 4096;
#pragma unroll
    for (int dn = 0; dn < 2; ++dn)
#pragma unroll
        for (int g = 0; g < 4; ++g) {
            uint32_t w0 = pack2(o_[dn][4 * g], o_[dn][4 * g + 1]);
            uint32_t w1 = pack2(o_[dn][4 * g + 2], o_[dn][4 * g + 3]);
            int c16 = (dn * 4 + g) ^ r7;
            *(uint2*)(eB + l31 * 128 + c16 * 16 + hi * 8) = make_uint2(w0, w1);
        }
    asm volatile("s_waitcnt lgkmcnt(0)" ::: "memory");
    int b = bh >> 4, h = bh & 15;
#pragma unroll
    for (int i = 0; i < 4; ++i) {
        int c = i * 64 + lane;
        int row = c >> 3;   // q within wave block
        int c16l = c & 7;   // d chunk
        bf16x8 ov = *(const bf16x8*)(eB + row * 128 + ((c16l ^ (row & 7)) << 4));
        *(bf16x8*)(Og + ((size_t)(b * T_SEQ + q0 + row)) * D_MODEL + h * HDIM + c16l * 8) = ov;
    }
}

// ---------------- launch ----------------
extern "C" void kernel_launch(void* const* d_in, const int* in_sizes, int n_in,
                              void* d_out, int out_size, void* d_ws, size_t ws_size,
                              hipStream_t stream) {
    const float* x = (const float*)d_in[0];
    const float* w_qkv = (const float*)d_in[1];
    const float* b_qkv = (const float*)d_in[2];
    const float* w_out = (const float*)d_in[3];
    const float* b_out = (const float*)d_in[4];
    float* out = (float*)d_out;
    char* ws = (char*)d_ws;

    unsigned short* x_bf   = (unsigned short*)(ws + 0);          // 8MB, reused as Vt later
    unsigned short* wqkv_t = (unsigned short*)(ws + 8388608);    // 6MB
    unsigned short* wout_t = (unsigned short*)(ws + 14680064);   // 2MB
    unsigned short* Qb     = (unsigned short*)(ws + 16777216);   // 8MB
    unsigned short* Kb     = (unsigned short*)(ws + 25165824);   // 8MB
    unsigned short* Vb     = (unsigned short*)(ws + 33554432);   // 8MB, reused as O later
    unsigned short* Vt     = x_bf;   // alias: x_bf dead after GEMM1
    unsigned short* Ob     = Vb;     // alias: V dead after transpose

    k_convert<<<MROWS * D_MODEL / 8 / 256, 256, 0, stream>>>((const float4*)x, (u16x8*)x_bf,
                                                             MROWS * D_MODEL / 8);
    k_transpose_conv<<<(D_MODEL / 32) * (3 * D_MODEL / 32), 256, 0, stream>>>(w_qkv, wqkv_t,
                                                                              D_MODEL, 3 * D_MODEL);
    k_transpose_conv<<<(D_MODEL / 32) * (D_MODEL / 32), 256, 0, stream>>>(w_out, wout_t,
                                                                          D_MODEL, D_MODEL);
    k_gemm<0><<<(MROWS / 128) * (3 * D_MODEL / 128), 256, 0, stream>>>(x_bf, wqkv_t, b_qkv,
                                                                       (void*)Qb, MROWS,
                                                                       3 * D_MODEL, D_MODEL);
    k_transpose_v<<<HEADS_TOTAL * (T_SEQ / 64), 256, 0, stream>>>(Vb, Vt);
    k_attn<<<512, 256, 0, stream>>>(Qb, Kb, Vt, Ob);
    k_gemm<1><<<(MROWS / 128) * (D_MODEL / 128), 256, 0, stream>>>(Ob, wout_t, b_out, (void*)out,
                                                                   MROWS, D_MODEL, D_MODEL);
}

// Round 6
// 238.541 us; speedup vs baseline: 1.0513x; 1.0513x over previous
//
#include <hip/hip_runtime.h>
#include <stdint.h>

typedef __bf16 bf16x8 __attribute__((ext_vector_type(8)));
typedef float f32x4 __attribute__((ext_vector_type(4)));
typedef float f32x16 __attribute__((ext_vector_type(16)));
typedef unsigned short u16x8 __attribute__((ext_vector_type(8)));
typedef uint32_t u32x4 __attribute__((ext_vector_type(4)));

#define D_MODEL 1024
#define T_SEQ 2048
#define BATCH 2
#define NHEAD 16
#define HDIM 64
#define MROWS (BATCH * T_SEQ)          // 4096
#define HEADS_TOTAL (BATCH * NHEAD)    // 32
#define QKV_ELEMS (HEADS_TOTAL * T_SEQ * HDIM)  // 4,194,304 per tensor

// Q scale folded with log2(e) so softmax runs in exp2 domain: 0.125 * log2(e)
#define QSCALE_LOG2 0.1803368801111204f

__device__ __forceinline__ unsigned short f32_to_bf16_rne(float f) {
    uint32_t u = __builtin_bit_cast(uint32_t, f);
    uint32_t r = (u + 0x7FFFu + ((u >> 16) & 1u)) >> 16;
    return (unsigned short)r;
}

__device__ __forceinline__ uint32_t pack2(float a, float b) {
    return (uint32_t)f32_to_bf16_rne(a) | ((uint32_t)f32_to_bf16_rne(b) << 16);
}

// bare v_exp_f32: computes 2^x in one TRANS-pipe instr (no libm fixup code)
__device__ __forceinline__ float exp2_hw(float x) {
    float r;
    asm("v_exp_f32 %0, %1" : "=v"(r) : "v"(x));
    return r;
}

__device__ __forceinline__ void gload_lds16(const void* g, void* l) {
    __builtin_amdgcn_global_load_lds(
        (const __attribute__((address_space(1))) void*)g,
        (__attribute__((address_space(3))) void*)l, 16, 0, 0);
}

__device__ __forceinline__ f32x4 mfma_bf16(bf16x8 a, bf16x8 b, f32x4 c) {
    return __builtin_amdgcn_mfma_f32_16x16x32_bf16(a, b, c, 0, 0, 0);
}
__device__ __forceinline__ f32x16 mfma32(bf16x8 a, bf16x8 b, f32x16 c) {
    return __builtin_amdgcn_mfma_f32_32x32x16_bf16(a, b, c, 0, 0, 0);
}

// ---------------- convert x: f32 -> bf16, 8 elems/thread ----------------
__global__ void k_convert(const float4* __restrict__ in, u16x8* __restrict__ out, int n8) {
    int i = blockIdx.x * 256 + threadIdx.x;
    if (i >= n8) return;
    float4 a = in[i * 2];
    float4 b = in[i * 2 + 1];
    u16x8 r;
    r[0] = f32_to_bf16_rne(a.x); r[1] = f32_to_bf16_rne(a.y);
    r[2] = f32_to_bf16_rne(a.z); r[3] = f32_to_bf16_rne(a.w);
    r[4] = f32_to_bf16_rne(b.x); r[5] = f32_to_bf16_rne(b.y);
    r[6] = f32_to_bf16_rne(b.z); r[7] = f32_to_bf16_rne(b.w);
    out[i] = r;
}

// ---------- transpose-convert: in f32 [R][C] -> out bf16 [C][R] ----------
__global__ void k_transpose_conv(const float* __restrict__ in, unsigned short* __restrict__ out,
                                 int R, int C) {
    __shared__ float tile[32][33];
    int nc = C >> 5;
    int tc0 = (blockIdx.x % nc) * 32;
    int tr0 = (blockIdx.x / nc) * 32;
    int tx = threadIdx.x & 31, ty = threadIdx.x >> 5;  // ty 0..7
#pragma unroll
    for (int i = 0; i < 4; ++i) {
        int r = ty * 4 + i;
        tile[r][tx] = in[(size_t)(tr0 + r) * C + tc0 + tx];
    }
    __syncthreads();
#pragma unroll
    for (int i = 0; i < 4; ++i) {
        int c = ty * 4 + i;
        out[(size_t)(tc0 + c) * R + tr0 + tx] = f32_to_bf16_rne(tile[tx][c]);
    }
}

// ---------------- GEMM: C[M][N] = A[M][K](bf16) @ Bt[N][K](bf16) + bias ----------------
// 128x128 tile, BK=32, 256 threads (4 waves 2x2), double-buffered LDS (2-phase pipeline).
template <int EPI>
__global__ __launch_bounds__(256) void k_gemm(const unsigned short* __restrict__ A,
                                              const unsigned short* __restrict__ Bt,
                                              const float* __restrict__ bias,
                                              void* __restrict__ outp,
                                              int M, int N, int K) {
    __shared__ __align__(16) unsigned short As[2][128 * 32];
    __shared__ __align__(16) unsigned short Bs[2][128 * 32];
    const int NB = N >> 7;
    int bm = blockIdx.x / NB, bn = blockIdx.x % NB;
    int tid = threadIdx.x;
    int lane = tid & 63, w = tid >> 6;
    int wr = w >> 1, wc = w & 1;
    int l15 = lane & 15, lg = lane >> 4;

    f32x4 acc[4][4] = {};

    const int nK = K >> 5;
    int c1 = tid, c2 = tid + 256;
    int r1 = c1 >> 2, o1 = (c1 & 3) * 8;
    int r2 = c2 >> 2, o2 = (c2 & 3) * 8;

#define GSTAGE(kt, buf)                                                          \
    do {                                                                         \
        int k0_ = (kt) * 32;                                                     \
        gload_lds16(A + (size_t)(bm * 128 + r1) * K + k0_ + o1,                  \
                    (char*)As[buf] + w * 1024);                                  \
        gload_lds16(A + (size_t)(bm * 128 + r2) * K + k0_ + o2,                  \
                    (char*)As[buf] + 4096 + w * 1024);                           \
        gload_lds16(Bt + (size_t)(bn * 128 + r1) * K + k0_ + o1,                 \
                    (char*)Bs[buf] + w * 1024);                                  \
        gload_lds16(Bt + (size_t)(bn * 128 + r2) * K + k0_ + o2,                 \
                    (char*)Bs[buf] + 4096 + w * 1024);                           \
    } while (0)

    GSTAGE(0, 0);
    __syncthreads();

    for (int kt = 0; kt < nK; ++kt) {
        int cur = kt & 1;
        if (kt + 1 < nK) GSTAGE(kt + 1, cur ^ 1);

        const unsigned short* Ac = As[cur];
        const unsigned short* Bc = Bs[cur];
        bf16x8 af[4], bfr[4];
#pragma unroll
        for (int i = 0; i < 4; ++i)
            af[i] = *(const bf16x8*)(Ac + (wr * 64 + i * 16 + l15) * 32 + lg * 8);
#pragma unroll
        for (int j = 0; j < 4; ++j)
            bfr[j] = *(const bf16x8*)(Bc + (wc * 64 + j * 16 + l15) * 32 + lg * 8);
#pragma unroll
        for (int i = 0; i < 4; ++i)
#pragma unroll
            for (int j = 0; j < 4; ++j)
                acc[i][j] = mfma_bf16(af[i], bfr[j], acc[i][j]);
        __syncthreads();
    }
#undef GSTAGE

    if (EPI == 1) {
        float* out = (float*)outp;
#pragma unroll
        for (int jn = 0; jn < 4; ++jn) {
            int n = bn * 128 + wc * 64 + jn * 16 + l15;
            float bv = bias[n];
#pragma unroll
            for (int i = 0; i < 4; ++i) {
#pragma unroll
                for (int j = 0; j < 4; ++j) {
                    int m = bm * 128 + wr * 64 + i * 16 + lg * 4 + j;
                    out[(size_t)m * N + n] = acc[i][jn][j] + bv;
                }
            }
        }
    } else {
        unsigned short* qkv = (unsigned short*)outp;
#pragma unroll
        for (int jn = 0; jn < 4; ++jn) {
            int n = bn * 128 + wc * 64 + jn * 16 + l15;
            float bv = bias[n];
            int part = n >> 10;          // 0=q 1=k 2=v
            int cc = n & 1023;
            int h = cc >> 6, d = cc & 63;
            float scale = (part == 0) ? QSCALE_LOG2 : 1.0f;
            unsigned short* dst = qkv + (size_t)part * QKV_ELEMS;
#pragma unroll
            for (int i = 0; i < 4; ++i) {
#pragma unroll
                for (int j = 0; j < 4; ++j) {
                    int m = bm * 128 + wr * 64 + i * 16 + lg * 4 + j;
                    int b = m >> 11, t = m & 2047;
                    float v = (acc[i][jn][j] + bv) * scale;
                    dst[((size_t)(b * NHEAD + h) * T_SEQ + t) * HDIM + d] = f32_to_bf16_rne(v);
                }
            }
        }
    }
}

// ---------------- V transpose: [bh][t][d] -> [bh][d][t] ----------------
__global__ void k_transpose_v(const unsigned short* __restrict__ V, unsigned short* __restrict__ Vt) {
    __shared__ unsigned short tile[64][66];
    int bh = blockIdx.x >> 5;
    int t0 = (blockIdx.x & 31) * 64;
    const unsigned short* Vb = V + (size_t)bh * T_SEQ * HDIM;
    unsigned short* Vtb = Vt + (size_t)bh * HDIM * T_SEQ;
    int d = threadIdx.x & 63, tq = threadIdx.x >> 6;
#pragma unroll
    for (int r = 0; r < 16; ++r) {
        int tl = tq * 16 + r;
        tile[tl][d] = Vb[(size_t)(t0 + tl) * HDIM + d];
    }
    __syncthreads();
    int tl = threadIdx.x & 63, dq = threadIdx.x >> 6;
#pragma unroll
    for (int r = 0; r < 16; ++r) {
        int dd = dq * 16 + r;
        Vtb[(size_t)dd * T_SEQ + t0 + tl] = tile[tl][dd];
    }
}

// ---------------- flash attention, 32x32 MFMA, swapped operands ----------------
// grid = 1024, xcd-pinned. block = 128 (2 waves x 32 q-rows) -> 4 independent
// barrier domains per CU (de-lockstep; pipes overlap across blocks).
// KVBLK=64 double-buffered LDS (32KB/block). QK^T as mfma(K,Q) -> S^T
// (q = lane&31 -> lane-local softmax, exp2 domain, bare v_exp_f32).
// PV B-frag built in-register with pack2 + pre-selected __shfl_xor(32).
// Defer-max: skip O-rescale while tile max grows < 8 (log2 units).
// l-sum tree placed AFTER PV so VALU overlaps MFMA.
__global__ __launch_bounds__(128) void k_attn(const unsigned short* __restrict__ Qg,
                                              const unsigned short* __restrict__ Kg,
                                              const unsigned short* __restrict__ Vtg,
                                              unsigned short* __restrict__ Og) {
    __shared__ __align__(16) unsigned short Ks[2][64 * 64];
    __shared__ __align__(16) unsigned short Vs[2][64 * 64];

    const int NT = T_SEQ / 64;  // 32
    int bid = blockIdx.x;
    int idx = bid >> 3;
    int bh = (bid & 7) * 4 + (idx >> 5);   // 8 xcds x 4 heads
    int qt = idx & 31;                      // 32 q-tiles of 64 rows
    int tid = threadIdx.x;
    int w = tid >> 6, lane = tid & 63;
    int l31 = lane & 31, hi = lane >> 5;
    int r7 = l31 & 7;

    const unsigned short* Qb = Qg + (size_t)bh * T_SEQ * HDIM;
    const unsigned short* Kb = Kg + (size_t)bh * T_SEQ * HDIM;
    const unsigned short* Vb = Vtg + (size_t)bh * HDIM * T_SEQ;

    int q0 = qt * 64 + w * 32;

    bf16x8 qf[4];
#pragma unroll
    for (int ks = 0; ks < 4; ++ks)
        qf[ks] = *(const bf16x8*)(Qb + (size_t)(q0 + l31) * HDIM + ks * 16 + hi * 8);

    f32x16 o_[2] = {};
    float m = -INFINITY, l = 0.f;

    // hoisted staging pointers: swizzle cs is i_-invariant (i_*16 == 0 mod 8)
    int r0 = tid >> 3;                       // 0..15
    int cs = (tid & 7) ^ (r0 & 7);
    const unsigned short* kp = Kb + r0 * HDIM + cs * 8;   // += 64*HDIM per tile
    const unsigned short* vp = Vb + (size_t)r0 * T_SEQ + cs * 8;  // += 64 per tile

    auto stage = [&](int buf) {
#pragma unroll
        for (int i_ = 0; i_ < 4; ++i_) {
            gload_lds16(kp + i_ * (16 * HDIM), (char*)Ks[buf] + i_ * 2048 + w * 1024);
            gload_lds16(vp + i_ * (16 * T_SEQ), (char*)Vs[buf] + i_ * 2048 + w * 1024);
        }
        kp += 64 * HDIM;
        vp += 64;
    };

    stage(0);
    __syncthreads();

    for (int t = 0; t < NT; ++t) {
        int cur = t & 1;
        if (t + 1 < NT) stage(cur ^ 1);

        const char* Kt = (const char*)Ks[cur];
        const char* Vt_ = (const char*)Vs[cur];

        // QK^T: S^T[kv][q]
        f32x16 s_[2] = {};
        __builtin_amdgcn_s_setprio(1);
#pragma unroll
        for (int ti = 0; ti < 2; ++ti) {
            int row = ti * 32 + l31;
#pragma unroll
            for (int ks = 0; ks < 4; ++ks) {
                bf16x8 kf = *(const bf16x8*)(Kt + row * 128 + ((((ks << 1) | hi) ^ r7) << 4));
                s_[ti] = mfma32(kf, qf[ks], s_[ti]);
            }
        }
        __builtin_amdgcn_s_setprio(0);

        // tree max over 32 lane-local entries + hi-half exchange
        float t16[16];
#pragma unroll
        for (int rr = 0; rr < 16; ++rr) t16[rr] = fmaxf(s_[0][rr], s_[1][rr]);
#pragma unroll
        for (int st = 8; st >= 1; st >>= 1)
#pragma unroll
            for (int rr = 0; rr < 8; ++rr)
                if (rr < st) t16[rr] = fmaxf(t16[rr], t16[rr + st]);
        float mx = fmaxf(t16[0], __shfl_xor(t16[0], 32));

        // deferred rescale (log2 domain, THR = 8)
        if (__any(mx - m > 8.0f)) {
            float mn = fmaxf(m, mx);
            float sc = exp2_hw(m - mn);
            m = mn;
            l *= sc;
#pragma unroll
            for (int rr = 0; rr < 16; ++rr) {
                o_[0][rr] *= sc;
                o_[1][rr] *= sc;
            }
        }

        // P = 2^(s - m) via bare v_exp_f32
#pragma unroll
        for (int ti = 0; ti < 2; ++ti)
#pragma unroll
            for (int rr = 0; rr < 16; ++rr) s_[ti][rr] = exp2_hw(s_[ti][rr] - m);

        // build PV B-fragments in-register (pack2 + shfl_xor(32) exchange)
        bf16x8 pa[4];
#pragma unroll
        for (int ks = 0; ks < 4; ++ks) {
            int ti = ks >> 1, k1 = ks & 1;
            uint32_t PA = pack2(s_[ti][8 * k1 + 0], s_[ti][8 * k1 + 1]);
            uint32_t PC = pack2(s_[ti][8 * k1 + 2], s_[ti][8 * k1 + 3]);
            uint32_t PB = pack2(s_[ti][8 * k1 + 4], s_[ti][8 * k1 + 5]);
            uint32_t PD = pack2(s_[ti][8 * k1 + 6], s_[ti][8 * k1 + 7]);
            uint32_t u0 = hi ? PA : PB;
            uint32_t u1 = hi ? PC : PD;
            uint32_t x0 = (uint32_t)__shfl_xor((int)u0, 32);
            uint32_t x1 = (uint32_t)__shfl_xor((int)u1, 32);
            u32x4 ww;
            ww[0] = hi ? x0 : PA;
            ww[1] = hi ? x1 : PC;
            ww[2] = hi ? PB : x0;
            ww[3] = hi ? PD : x1;
            pa[ks] = __builtin_bit_cast(bf16x8, ww);
        }

        // PV: O^T[d][q] += V^T[d][kv] * P^T[kv][q]
        __builtin_amdgcn_s_setprio(1);
#pragma unroll
        for (int dn = 0; dn < 2; ++dn) {
            int row = dn * 32 + l31;
#pragma unroll
            for (int ks = 0; ks < 4; ++ks) {
                bf16x8 vf = *(const bf16x8*)(Vt_ + row * 128 + ((((ks << 1) | hi) ^ r7) << 4));
                o_[dn] = mfma32(vf, pa[ks], o_[dn]);
            }
        }
        __builtin_amdgcn_s_setprio(0);

        // l-sum tree AFTER PV (overlaps MFMA)
        float a16[16];
#pragma unroll
        for (int rr = 0; rr < 16; ++rr) a16[rr] = s_[0][rr] + s_[1][rr];
#pragma unroll
        for (int st = 8; st >= 1; st >>= 1)
#pragma unroll
            for (int rr = 0; rr < 8; ++rr)
                if (rr < st) a16[rr] += a16[rr + st];
        l += a16[0] + __shfl_xor(a16[0], 32);

        __syncthreads();
    }

    // epilogue: divide by l, transpose O^T -> O via LDS (reuse dead Ks), store coalesced
    float inv = 1.0f / l;
#pragma unroll
    for (int rr = 0; rr < 16; ++rr) {
        o_[0][rr] *= inv;
        o_[1][rr] *= inv;
    }
    char* eB = (char*)Ks + (size_t)w * 4096;
#pragma unroll
    for (int dn = 0; dn < 2; ++dn)
#pragma unroll
        for (int g = 0; g < 4; ++g) {
            uint32_t w0 = pack2(o_[dn][4 * g], o_[dn][4 * g + 1]);
            uint32_t w1 = pack2(o_[dn][4 * g + 2], o_[dn][4 * g + 3]);
            int c16 = (dn * 4 + g) ^ r7;
            *(uint2*)(eB + l31 * 128 + c16 * 16 + hi * 8) = make_uint2(w0, w1);
        }
    asm volatile("s_waitcnt lgkmcnt(0)" ::: "memory");
    int b = bh >> 4, h = bh & 15;
#pragma unroll
    for (int i = 0; i < 4; ++i) {
        int c = i * 64 + lane;
        int row = c >> 3;   // q within wave block
        int c16l = c & 7;   // d chunk
        bf16x8 ov = *(const bf16x8*)(eB + row * 128 + ((c16l ^ (row & 7)) << 4));
        *(bf16x8*)(Og + ((size_t)(b * T_SEQ + q0 + row)) * D_MODEL + h * HDIM + c16l * 8) = ov;
    }
}

// ---------------- launch ----------------
extern "C" void kernel_launch(void* const* d_in, const int* in_sizes, int n_in,
                              void* d_out, int out_size, void* d_ws, size_t ws_size,
                              hipStream_t stream) {
    const float* x = (const float*)d_in[0];
    const float* w_qkv = (const float*)d_in[1];
    const float* b_qkv = (const float*)d_in[2];
    const float* w_out = (const float*)d_in[3];
    const float* b_out = (const float*)d_in[4];
    float* out = (float*)d_out;
    char* ws = (char*)d_ws;

    unsigned short* x_bf   = (unsigned short*)(ws + 0);          // 8MB, reused as Vt later
    unsigned short* wqkv_t = (unsigned short*)(ws + 8388608);    // 6MB
    unsigned short* wout_t = (unsigned short*)(ws + 14680064);   // 2MB
    unsigned short* Qb     = (unsigned short*)(ws + 16777216);   // 8MB
    unsigned short* Kb     = (unsigned short*)(ws + 25165824);   // 8MB
    unsigned short* Vb     = (unsigned short*)(ws + 33554432);   // 8MB, reused as O later
    unsigned short* Vt     = x_bf;   // alias: x_bf dead after GEMM1
    unsigned short* Ob     = Vb;     // alias: V dead after transpose

    k_convert<<<MROWS * D_MODEL / 8 / 256, 256, 0, stream>>>((const float4*)x, (u16x8*)x_bf,
                                                             MROWS * D_MODEL / 8);
    k_transpose_conv<<<(D_MODEL / 32) * (3 * D_MODEL / 32), 256, 0, stream>>>(w_qkv, wqkv_t,
                                                                              D_MODEL, 3 * D_MODEL);
    k_transpose_conv<<<(D_MODEL / 32) * (D_MODEL / 32), 256, 0, stream>>>(w_out, wout_t,
                                                                          D_MODEL, D_MODEL);
    k_gemm<0><<<(MROWS / 128) * (3 * D_MODEL / 128), 256, 0, stream>>>(x_bf, wqkv_t, b_qkv,
                                                                       (void*)Qb, MROWS,
                                                                       3 * D_MODEL, D_MODEL);
    k_transpose_v<<<HEADS_TOTAL * (T_SEQ / 64), 256, 0, stream>>>(Vb, Vt);
    k_attn<<<1024, 128, 0, stream>>>(Qb, Kb, Vt, Ob);
    k_gemm<1><<<(MROWS / 128) * (D_MODEL / 128), 256, 0, stream>>>(Ob, wout_t, b_out, (void*)out,
                                                                   MROWS, D_MODEL, D_MODEL);
}